// Round 4
// baseline (41.685 us; speedup 1.0000x reference)
//
#include <hip/hip_runtime.h>

#define B_ 4
#define T_ 8
#define N_ 256
#define F_ 16
#define D_ 64
#define NP (D_/2)       // 32 pairs per row
#define CHUNK 8
#define NCH (N_/CHUNK)  // 32 -> main grid = 1024 blocks (4/CU)

#define SC 2.8853900817779268f        // 2*log2(e): exp2(SC*x) = e^{2x}
#define LOG2E 1.4426950408889634f

__device__ __forceinline__ float fast_exp2(float x) { return __builtin_amdgcn_exp2f(x); }
__device__ __forceinline__ float fast_rcp(float x)  { return __builtin_amdgcn_rcpf(x); }

// ---------------- prologue ----------------
// q-rows -> combG[row][pr] = (eq_{2pr}, eq_{2pr+1}, 2wt_{2pr}, 2wt_{2pr+1})
// k-rows -> Ek[row][d] = exp2(SC*(k Wk + bk)_d)
__global__ __launch_bounds__(256)
void tattn_proj_kernel(const float* __restrict__ query,
                       const float* __restrict__ keys,
                       const float* __restrict__ Wq, const float* __restrict__ bq,
                       const float* __restrict__ Wk, const float* __restrict__ bk,
                       const float* __restrict__ wt,
                       float4* __restrict__ combG, float* __restrict__ Ek)
{
    const int tid = threadIdx.x;
    const int row = blockIdx.x * 4 + (tid >> 6);   // 4 rows (waves) per block
    const int j   = tid & 63;
    const int NQ  = B_ * N_;

    if (row < NQ) {                                // wave-uniform branch
        const float* in = query + (size_t)row * F_;
        float acc = bq[j];
        #pragma unroll
        for (int f = 0; f < F_; ++f) acc = fmaf(in[f], Wq[f * D_ + j], acc);
        float eq = fast_exp2(acc * SC);
        float partner = __shfl_xor(eq, 1);         // eq of d^1
        if ((j & 1) == 0) {
            combG[(size_t)row * NP + (j >> 1)] =
                make_float4(eq, partner, 2.0f * wt[j], 2.0f * wt[j + 1]);
        }
    } else {
        const int r = row - NQ;                    // r = (b*T+t)*N + n
        const float* in = keys + (size_t)r * F_;
        float acc = bk[j];
        #pragma unroll
        for (int f = 0; f < F_; ++f) acc = fmaf(in[f], Wk[f * D_ + j], acc);
        Ek[(size_t)r * D_ + j] = fast_exp2(acc * SC);
    }
}

// ---------------- main: scores + softmax ----------------
// score(n,m) = Wsum - sum_pairs (2w0(1+x1)+2w1(1+x0)) * rcp((1+x0)(1+x1)),  x_d = eq_d * ek_d
// comb reads are wave-uniform from const restrict global -> SMEM s_load (SGPR operands)
__global__ __launch_bounds__(256, 4)
void tattn_main_kernel(const float4* __restrict__ combG,
                       const float* __restrict__ Ek,
                       const float* __restrict__ wt,
                       float* __restrict__ out)
{
    __shared__ float partial[CHUNK][4];           // per-row per-wave sums (128 B)

    const int tid = threadIdx.x;
    const int bid = blockIdx.x;
    const int ch  = bid % NCH;
    const int t   = (bid / NCH) % T_;
    const int b   = bid / (NCH * T_);
    const int n0  = ch * CHUNK;

    // Ek row for this thread's key m=tid: 64 floats in registers
    float kreg[D_];
    {
        const float* kp = Ek + (((size_t)(b * T_ + t)) * N_ + tid) * D_;
        #pragma unroll
        for (int d = 0; d < D_; d += 4) {
            float4 v = *reinterpret_cast<const float4*>(kp + d);
            kreg[d] = v.x; kreg[d+1] = v.y; kreg[d+2] = v.z; kreg[d+3] = v.w;
        }
    }

    // Wsum: uniform loads -> scalarized, once per block
    float Wsum = 0.f;
    #pragma unroll
    for (int d = 0; d < D_; ++d) Wsum += wt[d];

    const int lane = tid & 63;
    const int wid  = tid >> 6;
    float pv[CHUNK];

    #pragma unroll
    for (int nn = 0; nn < CHUNK; ++nn) {
        const float4* cg = combG + ((size_t)(b * N_ + n0 + nn)) * NP;  // uniform
        float a0 = 0.f, a1 = 0.f, a2 = 0.f, a3 = 0.f;
        #pragma unroll
        for (int pr = 0; pr < NP; ++pr) {
            float4 c = cg[pr];                        // uniform -> s_load
            float pA = fmaf(c.x, kreg[2*pr+0], 1.0f); // 1 + x0
            float qA = fmaf(c.y, kreg[2*pr+1], 1.0f); // 1 + x1
            float nA = fmaf(c.w, pA, c.z * qA);       // 2w0(1+x1) + 2w1(1+x0)
            float r  = fast_rcp(pA * qA);
            if      ((pr & 3) == 0) a0 = fmaf(nA, r, a0);
            else if ((pr & 3) == 1) a1 = fmaf(nA, r, a1);
            else if ((pr & 3) == 2) a2 = fmaf(nA, r, a2);
            else                    a3 = fmaf(nA, r, a3);
        }
        float score = Wsum - ((a0 + a1) + (a2 + a3));

        // softmax numerator (|score| <= sum|wt| ~ 4 -> no max subtraction)
        float p = fast_exp2(score * LOG2E);
        pv[nn] = p;
        float s = p;
        #pragma unroll
        for (int off = 32; off >= 1; off >>= 1) s += __shfl_xor(s, off);
        if (lane == 0) partial[nn][wid] = s;
    }
    __syncthreads();

    const size_t obase = ((size_t)((b * T_ + t) * N_ + n0)) * N_ + tid;
    #pragma unroll
    for (int nn = 0; nn < CHUNK; ++nn) {
        float tot = (partial[nn][0] + partial[nn][1]) + (partial[nn][2] + partial[nn][3]);
        out[obase + (size_t)nn * N_] = pv[nn] * fast_rcp(tot);
    }
}

extern "C" void kernel_launch(void* const* d_in, const int* in_sizes, int n_in,
                              void* d_out, int out_size, void* d_ws, size_t ws_size,
                              hipStream_t stream) {
    const float* query = (const float*)d_in[0];
    const float* keys  = (const float*)d_in[1];
    const float* Wq    = (const float*)d_in[2];
    const float* bq    = (const float*)d_in[3];
    const float* Wk    = (const float*)d_in[4];
    const float* bk    = (const float*)d_in[5];
    const float* wt    = (const float*)d_in[6];
    float* out = (float*)d_out;

    float4* combG = (float4*)d_ws;                        // B*N*NP float4 = 512 KB
    float*  Ek    = (float*)((char*)d_ws + (size_t)B_ * N_ * NP * sizeof(float4));
                                                          // B*T*N*D floats = 2 MB

    const int rows = B_ * N_ + B_ * T_ * N_;              // 9216, 4 rows/block
    hipLaunchKernelGGL(tattn_proj_kernel, dim3(rows / 4), dim3(256), 0, stream,
                       query, keys, Wq, bq, Wk, bk, wt, combG, Ek);

    hipLaunchKernelGGL(tattn_main_kernel, dim3(B_ * T_ * NCH), dim3(256), 0, stream,
                       combG, Ek, wt, out);
}

// Round 5
// 37.065 us; speedup vs baseline: 1.1246x; 1.1246x over previous
//
#include <hip/hip_runtime.h>

#define B_ 4
#define T_ 8
#define N_ 256
#define F_ 16
#define D_ 64
#define NP (D_/2)       // 32 pairs per row
#define CHUNK 8
#define NCH (N_/CHUNK)  // 32 -> main grid = 1024 blocks (4/CU)

#define SC 2.8853900817779268f        // 2*log2(e): exp2(SC*x) = e^{2x}
#define LOG2E 1.4426950408889634f

typedef __attribute__((ext_vector_type(16))) float f32x16;

__device__ __forceinline__ float fast_exp2(float x) { return __builtin_amdgcn_exp2f(x); }
__device__ __forceinline__ float fast_rcp(float x)  { return __builtin_amdgcn_rcpf(x); }

// ---------------- prologue ----------------
// q-rows -> combG[row][pr] = (eq_{2pr}, eq_{2pr+1}, 2wt_{2pr}, 2wt_{2pr+1})
// k-rows -> Ek[row][d] = exp2(SC*(k Wk + bk)_d)
__global__ __launch_bounds__(256)
void tattn_proj_kernel(const float* __restrict__ query,
                       const float* __restrict__ keys,
                       const float* __restrict__ Wq, const float* __restrict__ bq,
                       const float* __restrict__ Wk, const float* __restrict__ bk,
                       const float* __restrict__ wt,
                       float4* __restrict__ combG, float* __restrict__ Ek)
{
    const int tid = threadIdx.x;
    const int row = blockIdx.x * 4 + (tid >> 6);   // 4 rows (waves) per block
    const int j   = tid & 63;
    const int NQ  = B_ * N_;

    if (row < NQ) {                                // wave-uniform branch
        const float* in = query + (size_t)row * F_;
        float acc = bq[j];
        #pragma unroll
        for (int f = 0; f < F_; ++f) acc = fmaf(in[f], Wq[f * D_ + j], acc);
        float eq = fast_exp2(acc * SC);
        float partner = __shfl_xor(eq, 1);         // eq of d^1
        if ((j & 1) == 0) {
            combG[(size_t)row * NP + (j >> 1)] =
                make_float4(eq, partner, 2.0f * wt[j], 2.0f * wt[j + 1]);
        }
    } else {
        const int r = row - NQ;                    // r = (b*T+t)*N + n
        const float* in = keys + (size_t)r * F_;
        float acc = bk[j];
        #pragma unroll
        for (int f = 0; f < F_; ++f) acc = fmaf(in[f], Wk[f * D_ + j], acc);
        Ek[(size_t)r * D_ + j] = fast_exp2(acc * SC);
    }
}

// ---------------- main: scores + softmax ----------------
// score(n,m) = Wsum - sum_pairs (2w0(1+x1)+2w1(1+x0)) * rcp((1+x0)(1+x1)),  x_d = eq_d*ek_d
// comb operands arrive via explicit s_load_dwordx16 (scalar pipe) -> zero LDS/VMEM in hot loop
__global__ __launch_bounds__(256, 4)
void tattn_main_kernel(const float4* __restrict__ combG,
                       const float* __restrict__ Ek,
                       const float* __restrict__ wt,
                       float* __restrict__ out)
{
    __shared__ float pbuf[CHUNK][N_];             // per-row p values (8 KB)
    __shared__ float partial[CHUNK][4];           // per-row per-wave sums

    const int tid = threadIdx.x;
    const int bid = blockIdx.x;
    const int ch  = bid % NCH;
    const int t   = (bid / NCH) % T_;
    const int b   = bid / (NCH * T_);
    const int n0  = ch * CHUNK;

    // Ek row for this thread's key m=tid: 64 floats in registers
    float kreg[D_];
    {
        const float* kp = Ek + (((size_t)(b * T_ + t)) * N_ + tid) * D_;
        #pragma unroll
        for (int d = 0; d < D_; d += 4) {
            float4 v = *reinterpret_cast<const float4*>(kp + d);
            kreg[d] = v.x; kreg[d+1] = v.y; kreg[d+2] = v.z; kreg[d+3] = v.w;
        }
    }

    // Wsum: uniform loads -> scalarized once
    float Wsum = 0.f;
    #pragma unroll
    for (int d = 0; d < D_; ++d) Wsum += wt[d];

    const int lane = tid & 63;
    const int wid  = tid >> 6;

    #pragma unroll 1
    for (int nn = 0; nn < CHUNK; ++nn) {
        const char* base = (const char*)(combG + ((size_t)(b * N_ + n0 + nn)) * NP); // 512 B/row, uniform
        float a0 = 0.f, a1 = 0.f, a2 = 0.f, a3 = 0.f;

        #pragma unroll
        for (int g = 0; g < 4; ++g) {             // 4 groups x 8 pairs
            f32x16 c0, c1;
            const float* p0 = (const float*)(base + g * 128);
            const float* p1 = (const float*)(base + g * 128 + 64);
            asm volatile("s_load_dwordx16 %0, %2, 0x0\n\t"
                         "s_load_dwordx16 %1, %3, 0x0"
                         : "=s"(c0), "=s"(c1)
                         : "s"(p0), "s"(p1));
            // dependence-correct drain: consumers read the post-wait SSA values
            asm volatile("s_waitcnt lgkmcnt(0)" : "+s"(c0), "+s"(c1));

            #pragma unroll
            for (int i = 0; i < 4; ++i) {
                {   // pairs g*8 + i  (from c0)
                    const int pr = g * 8 + i;
                    float pA = fmaf(c0[4*i+0], kreg[2*pr+0], 1.0f);
                    float qA = fmaf(c0[4*i+1], kreg[2*pr+1], 1.0f);
                    float nA = fmaf(c0[4*i+3], pA, c0[4*i+2] * qA);
                    float r  = fast_rcp(pA * qA);
                    if      ((pr & 3) == 0) a0 = fmaf(nA, r, a0);
                    else if ((pr & 3) == 1) a1 = fmaf(nA, r, a1);
                    else if ((pr & 3) == 2) a2 = fmaf(nA, r, a2);
                    else                    a3 = fmaf(nA, r, a3);
                }
                {   // pairs g*8 + 4 + i  (from c1)
                    const int pr = g * 8 + 4 + i;
                    float pA = fmaf(c1[4*i+0], kreg[2*pr+0], 1.0f);
                    float qA = fmaf(c1[4*i+1], kreg[2*pr+1], 1.0f);
                    float nA = fmaf(c1[4*i+3], pA, c1[4*i+2] * qA);
                    float r  = fast_rcp(pA * qA);
                    if      ((pr & 3) == 0) a0 = fmaf(nA, r, a0);
                    else if ((pr & 3) == 1) a1 = fmaf(nA, r, a1);
                    else if ((pr & 3) == 2) a2 = fmaf(nA, r, a2);
                    else                    a3 = fmaf(nA, r, a3);
                }
            }
        }
        float score = Wsum - ((a0 + a1) + (a2 + a3));

        // softmax numerator (|score| <= sum|wt| ~ 4 -> no max subtraction)
        float p = fast_exp2(score * LOG2E);
        pbuf[nn][tid] = p;
        float s = p;
        #pragma unroll
        for (int off = 32; off >= 1; off >>= 1) s += __shfl_xor(s, off);
        if (lane == 0) partial[nn][wid] = s;
    }
    __syncthreads();

    const size_t obase = ((size_t)((b * T_ + t) * N_ + n0)) * N_ + tid;
    #pragma unroll
    for (int nn = 0; nn < CHUNK; ++nn) {
        float tot = (partial[nn][0] + partial[nn][1]) + (partial[nn][2] + partial[nn][3]);
        out[obase + (size_t)nn * N_] = pbuf[nn][tid] * fast_rcp(tot);
    }
}

extern "C" void kernel_launch(void* const* d_in, const int* in_sizes, int n_in,
                              void* d_out, int out_size, void* d_ws, size_t ws_size,
                              hipStream_t stream) {
    const float* query = (const float*)d_in[0];
    const float* keys  = (const float*)d_in[1];
    const float* Wq    = (const float*)d_in[2];
    const float* bq    = (const float*)d_in[3];
    const float* Wk    = (const float*)d_in[4];
    const float* bk    = (const float*)d_in[5];
    const float* wt    = (const float*)d_in[6];
    float* out = (float*)d_out;

    float4* combG = (float4*)d_ws;                        // B*N*NP float4 = 512 KB
    float*  Ek    = (float*)((char*)d_ws + (size_t)B_ * N_ * NP * sizeof(float4));
                                                          // B*T*N*D floats = 2 MB

    const int rows = B_ * N_ + B_ * T_ * N_;              // 9216, 4 rows/block
    hipLaunchKernelGGL(tattn_proj_kernel, dim3(rows / 4), dim3(256), 0, stream,
                       query, keys, Wq, bq, Wk, bk, wt, combG, Ek);

    hipLaunchKernelGGL(tattn_main_kernel, dim3(B_ * T_ * NCH), dim3(256), 0, stream,
                       combG, Ek, wt, out);
}

// Round 6
// 30.476 us; speedup vs baseline: 1.3678x; 1.2162x over previous
//
#include <hip/hip_runtime.h>

#define B_ 4
#define T_ 8
#define N_ 256
#define F_ 16
#define D_ 64
#define NP (D_/2)       // 32 pairs per row
#define CHUNK 8
#define NCH (N_/CHUNK)  // 32 -> main grid = 1024 blocks

#define SC 2.8853900817779268f        // 2*log2(e): exp2(SC*x) = e^{2x}
#define LOG2E 1.4426950408889634f

typedef __attribute__((ext_vector_type(16))) float f32x16;

__device__ __forceinline__ float fast_exp2(float x) { return __builtin_amdgcn_exp2f(x); }
__device__ __forceinline__ float fast_rcp(float x)  { return __builtin_amdgcn_rcpf(x); }

// ---------------- prologue ----------------
// Eq[row][d] = exp2(SC*(q Wq + bq)_d);  Ek[row][d] = exp2(SC*(k Wk + bk)_d)
__global__ __launch_bounds__(256)
void tattn_proj_kernel(const float* __restrict__ query,
                       const float* __restrict__ keys,
                       const float* __restrict__ Wq, const float* __restrict__ bq,
                       const float* __restrict__ Wk, const float* __restrict__ bk,
                       float* __restrict__ Eq, float* __restrict__ Ek)
{
    const int tid = threadIdx.x;
    const int row = blockIdx.x * 4 + (tid >> 6);   // 4 rows (waves) per block
    const int j   = tid & 63;
    const int NQ  = B_ * N_;

    if (row < NQ) {                                // wave-uniform branch
        const float* in = query + (size_t)row * F_;
        float acc = bq[j];
        #pragma unroll
        for (int f = 0; f < F_; ++f) acc = fmaf(in[f], Wq[f * D_ + j], acc);
        Eq[(size_t)row * D_ + j] = fast_exp2(acc * SC);
    } else {
        const int r = row - NQ;                    // r = (b*T+t)*N + n
        const float* in = keys + (size_t)r * F_;
        float acc = bk[j];
        #pragma unroll
        for (int f = 0; f < F_; ++f) acc = fmaf(in[f], Wk[f * D_ + j], acc);
        Ek[(size_t)r * D_ + j] = fast_exp2(acc * SC);
    }
}

// ---------------- main ----------------
// score(n,m) = Wsum - sum_pairs (2w0(1+x1)+2w1(1+x0)) * rcp((1+x0)(1+x1)), x_d = eq_d*ek_d
// eq: 4x s_load_dwordx16 -> SGPRs (one drain/row). wt: replicated VGPRs. ek: VGPRs.
// Hot loop: zero LDS, zero VMEM.
__global__ __launch_bounds__(256, 3)
void tattn_main_kernel(const float* __restrict__ Eq,
                       const float* __restrict__ Ek,
                       const float* __restrict__ wt,
                       float* __restrict__ out)
{
    __shared__ float pbuf[CHUNK][N_];   // 8 KB
    __shared__ float wls[D_];           // 2*wt staging
    __shared__ float totL[CHUNK];

    const int tid = threadIdx.x;
    const int bid = blockIdx.x;
    const int ch  = bid % NCH;
    const int t   = (bid / NCH) % T_;
    const int b   = bid / (NCH * T_);
    const int n0  = ch * CHUNK;

    if (tid < D_) wls[tid] = 2.0f * wt[tid];

    // Ek row for this thread's key m=tid: 64 floats in VGPRs
    float kreg[D_];
    {
        const float* kp = Ek + (((size_t)(b * T_ + t)) * N_ + tid) * D_;
        #pragma unroll
        for (int d = 0; d < D_; d += 4) {
            float4 v = *reinterpret_cast<const float4*>(kp + d);
            kreg[d] = v.x; kreg[d+1] = v.y; kreg[d+2] = v.z; kreg[d+3] = v.w;
        }
    }
    __syncthreads();

    // 2*wt into VGPRs via LDS reads (ds_read dest is always a VGPR -> can't scalarize)
    float wv[D_];
    #pragma unroll
    for (int d = 0; d < D_; d += 4) {
        float4 v = *reinterpret_cast<const float4*>(&wls[d]);
        wv[d] = v.x; wv[d+1] = v.y; wv[d+2] = v.z; wv[d+3] = v.w;
    }
    float Wsum = 0.f;
    #pragma unroll
    for (int d = 0; d < D_; ++d) Wsum += wv[d];
    Wsum *= 0.5f;

    const float* eqrow = Eq + ((size_t)(b * N_ + n0)) * D_;   // advances 256 B/row

    #pragma unroll 1
    for (int nn = 0; nn < CHUNK; ++nn) {
        f32x16 e0, e1, e2, e3;
        asm volatile("s_load_dwordx16 %0, %4, 0x0\n\t"
                     "s_load_dwordx16 %1, %4, 0x40\n\t"
                     "s_load_dwordx16 %2, %4, 0x80\n\t"
                     "s_load_dwordx16 %3, %4, 0xc0"
                     : "=&s"(e0), "=&s"(e1), "=&s"(e2), "=&s"(e3)
                     : "s"(eqrow));
        asm volatile("s_waitcnt lgkmcnt(0)"
                     : "+s"(e0), "+s"(e1), "+s"(e2), "+s"(e3));
        __builtin_amdgcn_sched_barrier(0);

        float a0 = 0.f, a1 = 0.f, a2 = 0.f, a3 = 0.f;
        #pragma unroll
        for (int pr = 0; pr < NP; ++pr) {
            float eqa, eqb;
            if      (pr <  8) { eqa = e0[2*pr];      eqb = e0[2*pr+1];      }
            else if (pr < 16) { eqa = e1[2*pr-16];   eqb = e1[2*pr-15];     }
            else if (pr < 24) { eqa = e2[2*pr-32];   eqb = e2[2*pr-31];     }
            else              { eqa = e3[2*pr-48];   eqb = e3[2*pr-47];     }
            float pA = fmaf(eqa, kreg[2*pr+0], 1.0f);   // 1 + x0   (1 SGPR operand)
            float qA = fmaf(eqb, kreg[2*pr+1], 1.0f);   // 1 + x1
            float nA = fmaf(wv[2*pr+1], pA, wv[2*pr] * qA);  // all-VGPR
            float r  = fast_rcp(pA * qA);
            if      ((pr & 3) == 0) a0 = fmaf(nA, r, a0);
            else if ((pr & 3) == 1) a1 = fmaf(nA, r, a1);
            else if ((pr & 3) == 2) a2 = fmaf(nA, r, a2);
            else                    a3 = fmaf(nA, r, a3);
        }
        float score = Wsum - ((a0 + a1) + (a2 + a3));

        // |score| <= sum|wt| ~ 8 -> no max subtraction needed
        pbuf[nn][tid] = fast_exp2(score * LOG2E);
        eqrow += D_;
    }
    __syncthreads();

    // per-row totals: wave w reduces rows 2w, 2w+1 (outside hot loop)
    const int lane = tid & 63;
    const int wid  = tid >> 6;
    #pragma unroll
    for (int rr = 0; rr < 2; ++rr) {
        const int row = wid * 2 + rr;
        float4 v = *reinterpret_cast<const float4*>(&pbuf[row][lane * 4]);
        float s = (v.x + v.y) + (v.z + v.w);
        #pragma unroll
        for (int off = 32; off >= 1; off >>= 1) s += __shfl_xor(s, off);
        if (lane == 0) totL[row] = s;
    }
    __syncthreads();

    const size_t obase = ((size_t)((b * T_ + t) * N_ + n0)) * N_ + tid;
    #pragma unroll
    for (int nn = 0; nn < CHUNK; ++nn)
        out[obase + (size_t)nn * N_] = pbuf[nn][tid] * fast_rcp(totL[nn]);
}

extern "C" void kernel_launch(void* const* d_in, const int* in_sizes, int n_in,
                              void* d_out, int out_size, void* d_ws, size_t ws_size,
                              hipStream_t stream) {
    const float* query = (const float*)d_in[0];
    const float* keys  = (const float*)d_in[1];
    const float* Wq    = (const float*)d_in[2];
    const float* bq    = (const float*)d_in[3];
    const float* Wk    = (const float*)d_in[4];
    const float* bk    = (const float*)d_in[5];
    const float* wt    = (const float*)d_in[6];
    float* out = (float*)d_out;

    float* Eq = (float*)d_ws;                          // B*N*D   = 65536 floats (256 KB)
    float* Ek = Eq + (size_t)B_ * N_ * D_;             // B*T*N*D = 524288 floats (2 MB)

    const int rows = B_ * N_ + B_ * T_ * N_;           // 9216, 4 rows/block
    hipLaunchKernelGGL(tattn_proj_kernel, dim3(rows / 4), dim3(256), 0, stream,
                       query, keys, Wq, bq, Wk, bk, Eq, Ek);

    hipLaunchKernelGGL(tattn_main_kernel, dim3(B_ * T_ * NCH), dim3(256), 0, stream,
                       Eq, Ek, wt, out);
}